// Round 4
// baseline (211.741 us; speedup 1.0000x reference)
//
#include <hip/hip_runtime.h>

// Problem: B=16, C=4, H=W=512. input [B,C,H,W] f32; target [B,C+1,H,W] f32,
// last channel a {0,1} mask. Output scalar:
//   (1/B) * sum_b [ cnt_b>0 ? sum_{c,hw} mask*(in-tg)^2 / (C*cnt_b) : 0 ]
//
// History: R1/R3 showed ~59 us regardless of occupancy (29% vs 48%) ->
// capacity-bound at 2.7 TB/s with a 9-stream x 1MiB-stride per-wave pattern.
// R2 lesson: NO __threadfence / fused finalize. R4: stage each block's
// contiguous 36 KB chunk via global_load_lds dwordx4 DMA (1 contiguous 1KB
// run per wave-issue, 9 per wave), compute from LDS.

#define BATCH 16
#define CHAN 4
#define HWPIX (512 * 512)                 // 262144 pixels per plane
#define PX_PER_BLOCK 1024                 // contiguous pixels per block
#define THREADS 256
#define WAVES (THREADS / 64)              // 4
#define CHUNKS_PER_BATCH (HWPIX / PX_PER_BLOCK)   // 256
#define TOTAL_BLOCKS (BATCH * CHUNKS_PER_BATCH)   // 4096
#define PLANES (2 * CHAN + 1)             // 9 (4 in + 4 tg + mask)
#define SEGS (PLANES * 4)                 // 36 segments of 1 KB (256 floats)
#define SEGS_PER_WAVE (SEGS / WAVES)      // 9

typedef __attribute__((address_space(3))) float       lds_f32;
typedef __attribute__((address_space(1))) const float g_f32c;

__global__ __launch_bounds__(THREADS) void masked_mse_partial(
    const float* __restrict__ input,
    const float* __restrict__ target,
    float* __restrict__ ws) {
    __shared__ float smem[PLANES * PX_PER_BLOCK];   // 36 KB -> 4 blocks/CU
    __shared__ float ss[WAVES], sc[WAVES];

    const int b = blockIdx.x / CHUNKS_PER_BATCH;
    const int k = blockIdx.x % CHUNKS_PER_BATCH;

    const float* inb = input  + (size_t)b * CHAN * HWPIX       + (size_t)k * PX_PER_BLOCK;
    const float* tgb = target + (size_t)b * (CHAN + 1) * HWPIX + (size_t)k * PX_PER_BLOCK;

    const int lane = threadIdx.x & 63;
    const int w    = threadIdx.x >> 6;

    // Async DMA global->LDS: wave w stages 1KB segments [w*9, w*9+9).
    // Segment s covers plane p = s/4, sub-KB s%4. LDS dest is wave-uniform
    // (smem + s*256); each lane's 16B lands at +lane*16 (HW rule).
#pragma unroll
    for (int j = 0; j < SEGS_PER_WAVE; ++j) {
        const int s   = w * SEGS_PER_WAVE + j;
        const int p   = s >> 2;
        const int sub = s & 3;
        const float* gp;
        if (p < CHAN) gp = inb + (size_t)p * HWPIX + sub * 256;
        else          gp = tgb + (size_t)(p - CHAN) * HWPIX + sub * 256;  // p==8 -> mask
        __builtin_amdgcn_global_load_lds(
            (g_f32c*)(gp + lane * 4),
            (lds_f32*)(smem + s * 256),
            16, 0, 0);
    }

    __syncthreads();   // drains vmcnt(0) (DMA complete) + barrier

    // Compute from LDS: thread t handles pixels [4t, 4t+4) of the chunk.
    const int t = threadIdx.x;
    float4 m4 = ((const float4*)(smem + 2 * CHAN * PX_PER_BLOCK))[t];
    float mx = (m4.x == 1.f) ? 1.f : 0.f;
    float my = (m4.y == 1.f) ? 1.f : 0.f;
    float mz = (m4.z == 1.f) ? 1.f : 0.f;
    float mw = (m4.w == 1.f) ? 1.f : 0.f;
    float cnt = mx + my + mz + mw;
    float s_acc = 0.f;
#pragma unroll
    for (int c = 0; c < CHAN; ++c) {
        float4 a  = ((const float4*)(smem + c * PX_PER_BLOCK))[t];
        float4 tt = ((const float4*)(smem + (CHAN + c) * PX_PER_BLOCK))[t];
        float dx = a.x - tt.x, dy = a.y - tt.y, dz = a.z - tt.z, dw = a.w - tt.w;
        s_acc += dx * dx * mx + dy * dy * my + dz * dz * mz + dw * dw * mw;
    }

    // wave-64 shuffle reduction
#pragma unroll
    for (int off = 32; off > 0; off >>= 1) {
        s_acc += __shfl_down(s_acc, off, 64);
        cnt   += __shfl_down(cnt, off, 64);
    }
    if (lane == 0) { ss[w] = s_acc; sc[w] = cnt; }
    __syncthreads();

    if (t == 0) {
        float S = 0.f, Cn = 0.f;
#pragma unroll
        for (int i = 0; i < WAVES; ++i) { S += ss[i]; Cn += sc[i]; }
        atomicAdd(&ws[2 * b],     S);
        atomicAdd(&ws[2 * b + 1], Cn);
    }
}

__global__ void masked_mse_final(const float* __restrict__ ws,
                                 float* __restrict__ out) {
    if (threadIdx.x == 0 && blockIdx.x == 0) {
        float acc = 0.f;
#pragma unroll
        for (int b = 0; b < BATCH; ++b) {
            float s  = ws[2 * b];
            float cb = ws[2 * b + 1] * (float)CHAN;   // C * #masked pixels
            acc += (cb > 0.f) ? (s / cb) : 0.f;
        }
        out[0] = acc / (float)BATCH;
    }
}

extern "C" void kernel_launch(void* const* d_in, const int* in_sizes, int n_in,
                              void* d_out, int out_size, void* d_ws, size_t ws_size,
                              hipStream_t stream) {
    const float* input  = (const float*)d_in[0];
    const float* target = (const float*)d_in[1];
    float* out = (float*)d_out;
    float* ws  = (float*)d_ws;

    // zero per-batch {sum, count} accumulators (d_ws is re-poisoned to 0xAA)
    hipMemsetAsync(ws, 0, 2 * BATCH * sizeof(float), stream);

    masked_mse_partial<<<dim3(TOTAL_BLOCKS), dim3(THREADS), 0, stream>>>(
        input, target, ws);
    masked_mse_final<<<1, 64, 0, stream>>>(ws, out);
}

// Round 5
// 182.331 us; speedup vs baseline: 1.1613x; 1.1613x over previous
//
#include <hip/hip_runtime.h>

// Problem: B=16, C=4, H=W=512. input [B,C,H,W] f32; target [B,C+1,H,W] f32,
// last channel a {0,1} mask. Output scalar:
//   (1/B) * sum_b [ cnt_b>0 ? sum_{c,hw} mask*(in-tg)^2 / (C*cnt_b) : 0 ]
//
// History: R1/R3 ~59 us regardless of occupancy (29/48%) with VGPR=24/40 ->
// compiler serialized the 9 loads/iter (2-3 outstanding/wave). R4 DMA-staging
// regressed (drain-serialized). R2 lesson: no __threadfence/fused finalize.
// R5: explicit depth-2 software pipeline -> 9 prefetch loads issued before
// each compute phase; mask used directly as multiplier (values are exact 0/1).

#define BATCH 16
#define CHAN 4
#define HWPIX (512 * 512)                       // 262144 pixels per plane
#define BLOCKS_PER_BATCH 64
#define THREADS 256
#define TOTAL_BLOCKS (BATCH * BLOCKS_PER_BATCH) // 1024
#define GROUPS (HWPIX / 4)                      // 65536 float4 groups/plane
#define GPB (GROUPS / BLOCKS_PER_BATCH)         // 1024 groups per block
#define ITERS (GPB / THREADS)                   // 4 iterations per thread
#define NPL (2 * CHAN + 1)                      // 9 streams

__global__ __launch_bounds__(THREADS) void masked_mse_partial(
    const float* __restrict__ input,
    const float* __restrict__ target,
    float* __restrict__ ws) {
    const int b   = blockIdx.x / BLOCKS_PER_BATCH;
    const int blk = blockIdx.x % BLOCKS_PER_BATCH;

    const float* inb = input  + (size_t)b * CHAN * HWPIX;
    const float* tgb = target + (size_t)b * (CHAN + 1) * HWPIX;

    const float4* pl[NPL];
#pragma unroll
    for (int c = 0; c < CHAN; ++c) {
        pl[c]        = (const float4*)(inb + (size_t)c * HWPIX);
        pl[CHAN + c] = (const float4*)(tgb + (size_t)c * HWPIX);
    }
    pl[2 * CHAN] = (const float4*)(tgb + (size_t)CHAN * HWPIX);   // mask

    const int g0 = blk * GPB + threadIdx.x;

    float4 cur[NPL], nxt[NPL];
#pragma unroll
    for (int j = 0; j < NPL; ++j) cur[j] = pl[j][g0];

    float s = 0.f, cnt = 0.f;

#pragma unroll
    for (int it = 0; it < ITERS; ++it) {
        // prefetch next iteration's 9 float4s BEFORE consuming cur ->
        // 9 KB in flight per wave during the compute+wait phase
        if (it + 1 < ITERS) {
            const int gn = g0 + (it + 1) * THREADS;
#pragma unroll
            for (int j = 0; j < NPL; ++j) nxt[j] = pl[j][gn];
        }

        float4 m = cur[2 * CHAN];        // exact 0.0/1.0 -> use directly
        cnt += m.x + m.y + m.z + m.w;
#pragma unroll
        for (int c = 0; c < CHAN; ++c) {
            float4 a = cur[c];
            float4 t = cur[CHAN + c];
            float dx = a.x - t.x, dy = a.y - t.y;
            float dz = a.z - t.z, dw = a.w - t.w;
            s += dx * dx * m.x + dy * dy * m.y + dz * dz * m.z + dw * dw * m.w;
        }

        if (it + 1 < ITERS) {
#pragma unroll
            for (int j = 0; j < NPL; ++j) cur[j] = nxt[j];
        }
    }

    // wave-64 shuffle reduction
#pragma unroll
    for (int off = 32; off > 0; off >>= 1) {
        s   += __shfl_down(s, off, 64);
        cnt += __shfl_down(cnt, off, 64);
    }

    __shared__ float ss[THREADS / 64];
    __shared__ float sc[THREADS / 64];
    const int lane = threadIdx.x & 63;
    const int wid  = threadIdx.x >> 6;
    if (lane == 0) { ss[wid] = s; sc[wid] = cnt; }
    __syncthreads();

    if (threadIdx.x == 0) {
        float S = 0.f, Cn = 0.f;
#pragma unroll
        for (int w = 0; w < THREADS / 64; ++w) { S += ss[w]; Cn += sc[w]; }
        atomicAdd(&ws[2 * b],     S);
        atomicAdd(&ws[2 * b + 1], Cn);
    }
}

__global__ void masked_mse_final(const float* __restrict__ ws,
                                 float* __restrict__ out) {
    if (threadIdx.x == 0 && blockIdx.x == 0) {
        float acc = 0.f;
#pragma unroll
        for (int b = 0; b < BATCH; ++b) {
            float s  = ws[2 * b];
            float cb = ws[2 * b + 1] * (float)CHAN;   // C * #masked pixels
            acc += (cb > 0.f) ? (s / cb) : 0.f;
        }
        out[0] = acc / (float)BATCH;
    }
}

extern "C" void kernel_launch(void* const* d_in, const int* in_sizes, int n_in,
                              void* d_out, int out_size, void* d_ws, size_t ws_size,
                              hipStream_t stream) {
    const float* input  = (const float*)d_in[0];
    const float* target = (const float*)d_in[1];
    float* out = (float*)d_out;
    float* ws  = (float*)d_ws;

    // zero per-batch {sum, count} accumulators (d_ws is re-poisoned to 0xAA)
    hipMemsetAsync(ws, 0, 2 * BATCH * sizeof(float), stream);

    masked_mse_partial<<<dim3(TOTAL_BLOCKS), dim3(THREADS), 0, stream>>>(
        input, target, ws);
    masked_mse_final<<<1, 64, 0, stream>>>(ws, out);
}

// Round 7
// 165.970 us; speedup vs baseline: 1.2758x; 1.0986x over previous
//
#include <hip/hip_runtime.h>

// Problem: B=16, C=4, H=W=512. input [B,C,H,W] f32; target [B,C+1,H,W] f32,
// last channel a {0,1} mask. Output scalar:
//   (1/B) * sum_b [ cnt_b>0 ? sum_{c,hw} mask*(in-tg)^2 / (C*cnt_b) : 0 ]
//
// History: R1/R3/R5 all ~59-61 us at 2.65 TB/s delivered regardless of
// occupancy/pipelining -> saturated shared resource. R4 DMA staging worse.
// R2: no __threadfence. R7 (=R6 fixed): 3 streams/block instead of 9
// (one channel per block), XCD-swizzled so the 4 c-blocks of a (b,chunk)
// unit share an L2 for the mask re-reads; nontemporal in/tg loads via
// native ext_vector_type (HIP_vector_type rejected by the builtin).

#define BATCH 16
#define CHAN 4
#define HWPIX (512 * 512)                 // 262144 pixels per plane
#define CHUNK_PX 16384                    // pixels per chunk
#define CPB (HWPIX / CHUNK_PX)            // 16 chunks per plane
#define UNITS (BATCH * CPB)               // 256 (b,k) units
#define THREADS 256
#define TOTAL_BLOCKS (UNITS * CHAN)       // 1024 blocks
#define G4 (CHUNK_PX / 4)                 // 4096 float4 per chunk-plane
#define ITERS (G4 / THREADS)              // 16 iterations per thread

typedef float vf4 __attribute__((ext_vector_type(4)));

__global__ __launch_bounds__(THREADS) void masked_mse_partial(
    const float* __restrict__ input,
    const float* __restrict__ target,
    float* __restrict__ ws) {
    // blockIdx swizzle: idx = q*32 + c*8 + r. All four c-blocks of unit
    // u=(q,r) are congruent mod 8 -> same XCD, dispatched within a 32-block
    // window -> mask chunk L2-hits on 3 of 4 reads.
    const int bid = blockIdx.x;
    const int r   = bid & 7;
    const int c   = (bid >> 3) & 3;
    const int q   = bid >> 5;
    const int u   = q * 8 + r;            // [0, 256)
    const int b   = u >> 4;               // u / CPB
    const int k   = u & (CPB - 1);

    const vf4* ip = (const vf4*)(input  + ((size_t)b * CHAN + c) * HWPIX
                                        + (size_t)k * CHUNK_PX);
    const vf4* tp = (const vf4*)(target + ((size_t)b * (CHAN + 1) + c) * HWPIX
                                        + (size_t)k * CHUNK_PX);
    const vf4* mp = (const vf4*)(target + ((size_t)b * (CHAN + 1) + CHAN) * HWPIX
                                        + (size_t)k * CHUNK_PX);

    float s = 0.f, cnt = 0.f;

    // 12 grouped loads (4 iters x 3 streams) before any use -> ~48 data
    // VGPRs live, deep MLP per wave.
    for (int it = 0; it < ITERS; it += 4) {
        const int g0 = it * THREADS + threadIdx.x;
        vf4 a0 = __builtin_nontemporal_load(&ip[g0]);
        vf4 a1 = __builtin_nontemporal_load(&ip[g0 + THREADS]);
        vf4 a2 = __builtin_nontemporal_load(&ip[g0 + 2 * THREADS]);
        vf4 a3 = __builtin_nontemporal_load(&ip[g0 + 3 * THREADS]);
        vf4 t0 = __builtin_nontemporal_load(&tp[g0]);
        vf4 t1 = __builtin_nontemporal_load(&tp[g0 + THREADS]);
        vf4 t2 = __builtin_nontemporal_load(&tp[g0 + 2 * THREADS]);
        vf4 t3 = __builtin_nontemporal_load(&tp[g0 + 3 * THREADS]);
        vf4 m0 = mp[g0];
        vf4 m1 = mp[g0 + THREADS];
        vf4 m2 = mp[g0 + 2 * THREADS];
        vf4 m3 = mp[g0 + 3 * THREADS];

        vf4 d0 = a0 - t0, d1 = a1 - t1, d2 = a2 - t2, d3 = a3 - t3;
        vf4 acc = d0 * d0 * m0 + d1 * d1 * m1 + d2 * d2 * m2 + d3 * d3 * m3;
        s += acc.x + acc.y + acc.z + acc.w;

        if (c == 0) {   // wave-uniform: count mask once per (b,k) unit
            vf4 mc = m0 + m1 + m2 + m3;
            cnt += mc.x + mc.y + mc.z + mc.w;
        }
    }

    // wave-64 shuffle reduction
#pragma unroll
    for (int off = 32; off > 0; off >>= 1) {
        s   += __shfl_down(s, off, 64);
        cnt += __shfl_down(cnt, off, 64);
    }

    __shared__ float ss[THREADS / 64];
    __shared__ float sc[THREADS / 64];
    const int lane = threadIdx.x & 63;
    const int wid  = threadIdx.x >> 6;
    if (lane == 0) { ss[wid] = s; sc[wid] = cnt; }
    __syncthreads();

    if (threadIdx.x == 0) {
        float S = 0.f, Cn = 0.f;
#pragma unroll
        for (int w = 0; w < THREADS / 64; ++w) { S += ss[w]; Cn += sc[w]; }
        atomicAdd(&ws[2 * b],     S);
        if (c == 0) atomicAdd(&ws[2 * b + 1], Cn);
    }
}

__global__ void masked_mse_final(const float* __restrict__ ws,
                                 float* __restrict__ out) {
    if (threadIdx.x == 0 && blockIdx.x == 0) {
        float acc = 0.f;
#pragma unroll
        for (int b = 0; b < BATCH; ++b) {
            float s  = ws[2 * b];
            float cb = ws[2 * b + 1] * (float)CHAN;   // C * #masked pixels
            acc += (cb > 0.f) ? (s / cb) : 0.f;
        }
        out[0] = acc / (float)BATCH;
    }
}

extern "C" void kernel_launch(void* const* d_in, const int* in_sizes, int n_in,
                              void* d_out, int out_size, void* d_ws, size_t ws_size,
                              hipStream_t stream) {
    const float* input  = (const float*)d_in[0];
    const float* target = (const float*)d_in[1];
    float* out = (float*)d_out;
    float* ws  = (float*)d_ws;

    // zero per-batch {sum, count} accumulators (d_ws is re-poisoned to 0xAA)
    (void)hipMemsetAsync(ws, 0, 2 * BATCH * sizeof(float), stream);

    masked_mse_partial<<<dim3(TOTAL_BLOCKS), dim3(THREADS), 0, stream>>>(
        input, target, ws);
    masked_mse_final<<<1, 64, 0, stream>>>(ws, out);
}